// Round 6
// baseline (2125.790 us; speedup 1.0000x reference)
//
#include <hip/hip_runtime.h>
#include <hip/hip_bf16.h>

#define N_BATCH 8
#define N_CH    16
#define N_SMP   480000
#define N_EARS  2
#define N_TAP   2048

#define NKT     65                    // K-tiles (of 32) per channel
#define ROWS    256                   // q-rows per block (4 waves x 4 msubs x 16)
#define N_QROWS (N_SMP / 16)          // 30000
#define QB_PER_B ((N_QROWS + ROWS - 1) / ROWS)   // 118
#define BLK     256
#define BQD     3                     // B prefetch depth (round-4: 6 spills)

typedef __bf16 bf16x8 __attribute__((ext_vector_type(8)));
typedef float  f32x4  __attribute__((ext_vector_type(4)));

// ---------------------------------------------------------------------------
// Prep: pack filters into MFMA-B-fragment order (verified rounds 1-2).
// B[u][n] = h[e][c][2048 - u + n], u = kt*32 + (lane>>4)*8 + j, n = lane&15.
// Flat: (((c*NKT + kt)*2 + e)*64 + lane)*8 + j  -> 16B/lane, coalesced.
// ---------------------------------------------------------------------------
__global__ void build_bpk(const float* __restrict__ h, __bf16* __restrict__ bpk)
{
    const int idx = blockIdx.x * 256 + threadIdx.x;
    const int total = N_CH * NKT * 2 * 64 * 8;
    if (idx >= total) return;

    const int j    = idx & 7;
    const int lane = (idx >> 3) & 63;
    const int e    = (idx >> 9) & 1;
    const int ckt  = idx >> 10;          // c*NKT + kt
    const int kt   = ckt % NKT;
    const int c    = ckt / NKT;

    const int n  = lane & 15;
    const int kq = (lane >> 4) * 8 + j;
    const int u  = kt * 32 + kq;
    const int k  = 2048 - u + n;

    float val = (k >= 0 && k < N_TAP) ? h[((long)e * N_CH + c) * N_TAP + k] : 0.0f;
    bpk[idx] = (__bf16)val;
}

// ---------------------------------------------------------------------------
// A-fragment load straight from global, hardened branchless form:
// 8 consecutive fp32 at sample index t (t always == 0 mod 8 -> two aligned
// float4 with ONE shared OOB predicate: every OOB float4 is fully OOB).
// Address is clamped into [0, N_SMP-8] so no lane can ever leave the channel
// row regardless of t; OOB fragments are zero-filled via vector select --
// bit-identical to the old staged-LDS zero-fill semantics.
// ---------------------------------------------------------------------------
__device__ __forceinline__ bf16x8 ldf(const float* __restrict__ x, int t)
{
    int tc = t < 0 ? 0 : t;
    tc = tc > (N_SMP - 8) ? (N_SMP - 8) : tc;
    const float4 a  = *(const float4*)(x + tc);
    const float4 b2 = *(const float4*)(x + tc + 4);
    union { __bf16 h[8]; bf16x8 v; } r;
    r.h[0] = (__bf16)a.x;  r.h[1] = (__bf16)a.y;
    r.h[2] = (__bf16)a.z;  r.h[3] = (__bf16)a.w;
    r.h[4] = (__bf16)b2.x; r.h[5] = (__bf16)b2.y;
    r.h[6] = (__bf16)b2.z; r.h[7] = (__bf16)b2.w;
    const bf16x8 z = {};
    return (t == tc) ? r.v : z;
}

// ---------------------------------------------------------------------------
// Main GEMM -- round-3 winner schedule (W[4][8] banked window, spread
// 1-per-kt refills, setprio around MFMA clusters, BQD=3) with LDS staging
// REMOVED: W preload/refill read global directly (f(j) = x[tw + 32j .. +7]).
// Rationale: per wave the A-stream is one sequential pass over a private
// 12.3 KB window (4x in-register msub reuse; the 8x j-overlap re-reads hit a
// ~2 KB sliding window held by L1; HBM sees the same unique footprint).
// Removing staging kills ALL barriers, the staged-load vmcnt force-drain,
// and the LDS round-trip -- waves become fully decoupled self-paced streams,
// so co-resident waves cover each other's channel-boundary ramps instead of
// stalling together at a barrier (round-3: ~43% correlated-idle).
// Round-5 lesson: dual-template instantiation + unclamped checked loads
// crashed unexplainably; this version is single-path with clamped addresses.
// ---------------------------------------------------------------------------
__global__ __launch_bounds__(BLK, 2)
void hoa_bin_gemm(const float* __restrict__ hoa,
                  const __bf16* __restrict__ bpk,
                  float* __restrict__ out)
{
    const int qb   = blockIdx.x;          // 0..117
    const int b    = blockIdx.y;          // 0..7
    const int tid  = threadIdx.x;
    const int lane = tid & 63;
    const int wv   = tid >> 6;            // wave 0..3
    const int mlan = lane & 15;
    const int quad = lane >> 4;

    const int q0 = qb * ROWS;
    const int t0 = 16 * q0 - 2048;        // sample index of f-window origin

    const int abase = wv * 1024 + 16 * mlan + 8 * quad;
    const int tw    = t0 + abase;         // per-lane base sample for f(0)

    const float* xb = hoa + (long)b * N_CH * N_SMP;

    f32x4 acc[4][2] = {};                 // [msub][ear]

    for (int c = 0; c < N_CH; ++c) {
        const __bf16* bp = bpk + (long)c * (NKT * 1024) + lane * 8;
        const float*  xc = xb + (long)c * N_SMP;

        // ---- prime B queue (depth BQD): L2 latency overlaps W preload ----
        bf16x8 BQ0[BQD], BQ1[BQD];
        #pragma unroll
        for (int d = 0; d < BQD; ++d) {
            BQ0[d] = *(const bf16x8*)(bp + d * 1024);
            BQ1[d] = *(const bf16x8*)(bp + d * 1024 + 512);
        }

        // ---- preload A window from global: bank s holds f(8s..8s+7) ----
        bf16x8 W[4][8];
        #pragma unroll
        for (int s = 0; s < 4; ++s)
            #pragma unroll
            for (int i = 0; i < 8; ++i)
                W[s][i] = ldf(xc, tw + 32 * (8 * s + i));

        // ---- 8 groups of 8 K-tiles; per-kt: {BQ refill, MFMA x8, W refill} ----
        #pragma unroll
        for (int g = 0; g < 8; ++g) {
            const int g4 = g & 3;
            #pragma unroll
            for (int i = 0; i < 8; ++i) {
                const int kt = 8 * g + i;
                const int d  = kt % BQD;
                bf16x8 b0 = BQ0[d];
                bf16x8 b1 = BQ1[d];
                const int ktp = (kt + BQD <= 64) ? kt + BQD : 64;   // compile-time
                BQ0[d] = *(const bf16x8*)(bp + ktp * 1024);
                BQ1[d] = *(const bf16x8*)(bp + ktp * 1024 + 512);
                __builtin_amdgcn_s_setprio(1);
                #pragma unroll
                for (int s = 0; s < 4; ++s) {
                    acc[s][0] = __builtin_amdgcn_mfma_f32_16x16x32_bf16(
                                    W[(g4 + s) & 3][i], b0, acc[s][0], 0, 0, 0);
                    acc[s][1] = __builtin_amdgcn_mfma_f32_16x16x32_bf16(
                                    W[(g4 + s) & 3][i], b1, acc[s][1], 0, 0, 0);
                }
                __builtin_amdgcn_s_setprio(0);
                // refill slot i of retiring bank g4 with f(8g+32+i)
                // (consumed 8+ kt later -> ample latency slack; g=7 slots
                // i>=1 are dead values, addresses clamped in-bounds)
                W[g4][i] = ldf(xc, tw + 32 * (8 * g + 32 + i));
            }
        }

        // ---- tail kt = 64: bank s slot 0 holds f(64+8s); BQ slot 64%BQD ----
        {
            bf16x8 b0 = BQ0[64 % BQD];
            bf16x8 b1 = BQ1[64 % BQD];
            __builtin_amdgcn_s_setprio(1);
            #pragma unroll
            for (int s = 0; s < 4; ++s) {
                acc[s][0] = __builtin_amdgcn_mfma_f32_16x16x32_bf16(
                                W[s][0], b0, acc[s][0], 0, 0, 0);
                acc[s][1] = __builtin_amdgcn_mfma_f32_16x16x32_bf16(
                                W[s][0], b1, acc[s][1], 0, 0, 0);
            }
            __builtin_amdgcn_s_setprio(0);
        }
    }

    // ---- epilogue: C/D layout row = quad*4 + r, col = lane&15 (verified) ----
    const long ob = (long)b * N_EARS * N_SMP;
    #pragma unroll
    for (int s = 0; s < 4; ++s) {
        #pragma unroll
        for (int e = 0; e < N_EARS; ++e) {
            #pragma unroll
            for (int r = 0; r < 4; ++r) {
                const int rl = wv * 64 + s * 16 + quad * 4 + r;
                const int q  = q0 + rl;
                if (q < N_QROWS)
                    out[ob + (long)e * N_SMP + 16 * q + mlan] = acc[s][e][r];
            }
        }
    }
}

// ---------------------------------------------------------------------------
extern "C" void kernel_launch(void* const* d_in, const int* in_sizes, int n_in,
                              void* d_out, int out_size, void* d_ws, size_t ws_size,
                              hipStream_t stream)
{
    const float* hoa = (const float*)d_in[0];   // [8,16,480000] fp32
    const float* h   = (const float*)d_in[1];   // [2,16,2048]  fp32
    float* out       = (float*)d_out;           // [8,2,480000] fp32
    __bf16* bpk      = (__bf16*)d_ws;           // 2,129,920 B filter pack

    const int total_bpk = N_CH * NKT * 2 * 64 * 8;          // 1,064,960
    build_bpk<<<(total_bpk + 255) / 256, 256, 0, stream>>>(h, bpk);

    dim3 grid(QB_PER_B, N_BATCH);
    hoa_bin_gemm<<<grid, BLK, 0, stream>>>(hoa, bpk, out);
}

// Round 7
// 775.934 us; speedup vs baseline: 2.7397x; 2.7397x over previous
//
#include <hip/hip_runtime.h>
#include <hip/hip_bf16.h>

#define N_BATCH 8
#define N_CH    16
#define N_SMP   480000
#define N_EARS  2
#define N_TAP   2048

#define NKT     65                    // K-tiles (of 32) per channel
#define ROWS    256                   // q-rows per block (4 waves x 4 msubs x 16)
#define N_QROWS (N_SMP / 16)          // 30000
#define QB_PER_B ((N_QROWS + ROWS - 1) / ROWS)   // 118
#define BLK     256
#define BQD     3                     // B prefetch depth (round-4: 6 spills)
#define WSEG    3328                  // bf16 elems per wave-private window buffer
                                      //   (max read offset 3311; 64B-aligned pad)

typedef __bf16 bf16x8 __attribute__((ext_vector_type(8)));
typedef float  f32x4  __attribute__((ext_vector_type(4)));

// ---------------------------------------------------------------------------
// Prep: pack filters into MFMA-B-fragment order (verified rounds 1-2).
// B[u][n] = h[e][c][2048 - u + n], u = kt*32 + (lane>>4)*8 + j, n = lane&15.
// Flat: (((c*NKT + kt)*2 + e)*64 + lane)*8 + j  -> 16B/lane, coalesced.
// ---------------------------------------------------------------------------
__global__ void build_bpk(const float* __restrict__ h, __bf16* __restrict__ bpk)
{
    const int idx = blockIdx.x * 256 + threadIdx.x;
    const int total = N_CH * NKT * 2 * 64 * 8;
    if (idx >= total) return;

    const int j    = idx & 7;
    const int lane = (idx >> 3) & 63;
    const int e    = (idx >> 9) & 1;
    const int ckt  = idx >> 10;          // c*NKT + kt
    const int kt   = ckt % NKT;
    const int c    = ckt / NKT;

    const int n  = lane & 15;
    const int kq = (lane >> 4) * 8 + j;
    const int u  = kt * 32 + kq;
    const int k  = 2048 - u + n;

    float val = (k >= 0 && k < N_TAP) ? h[((long)e * N_CH + c) * N_TAP + k] : 0.0f;
    bpk[idx] = (__bf16)val;
}

// ---------------------------------------------------------------------------
// Clamped float4 load (round-6's verified-correct hardened pattern): address
// clamped into [0, N_SMP-4] so no access can leave the channel row; fully-OOB
// float4s zero-filled (t is 4-aligned, so OOB is all-or-nothing per float4) --
// identical semantics to the old cooperative staged zero-fill.
// ---------------------------------------------------------------------------
__device__ __forceinline__ float4 ldx(const float* __restrict__ x, int t)
{
    int tc = t < 0 ? 0 : t;
    tc = tc > (N_SMP - 4) ? (N_SMP - 4) : tc;
    float4 v = *(const float4*)(x + tc);
    if (t != tc) { v.x = 0.f; v.y = 0.f; v.z = 0.f; v.w = 0.f; }
    return v;
}

__device__ __forceinline__ void st4(__bf16* __restrict__ xd, int i4, float4 v)
{
    union { __bf16 hh[4]; uint2 u; } pk;
    pk.hh[0] = (__bf16)v.x; pk.hh[1] = (__bf16)v.y;
    pk.hh[2] = (__bf16)v.z; pk.hh[3] = (__bf16)v.w;
    *(uint2*)(&xd[4 * i4]) = pk.u;
}

// ---------------------------------------------------------------------------
// Main GEMM -- round-3 winner schedule (W[4][8] banked window, spread
// 1-per-kt refills, setprio, BQD=3) with WAVE-PRIVATE LDS staging:
//   * each wave stages its OWN 3328-elem window xs[wv][buf] (its read span is
//     [t0+wv*1024, +3311] -- contiguous, overlapping neighbors' by ~2048)
//   * ZERO __syncthreads: no cross-wave LDS sharing -> no barrier, no full
//     vmcnt/lgkm drain, no correlated 8-wave stall at channel boundaries.
//     Waves self-pace; co-resident waves cover each other's ramps.
//   * staging = 13 float4/lane/channel (2.08x traffic of cooperative staging;
//     input is L3-resident and HBM is at 5% peak -> ~free), split into 7+6
//     batches with batch-1 written back mid-loop (legal: buffer is wave-own)
//     so transient regs stay at round-3's 28, not 52.
// Round-6 lesson: no-LDS fails (15x intra-wave Toeplitz redundancy thrashes
// L1 -> 1.3 GB HBM fetch, MfmaUtil 11%). LDS reuse is structurally required;
// only the BARRIER was the enemy.
// ---------------------------------------------------------------------------
__global__ __launch_bounds__(BLK, 2)
void hoa_bin_gemm(const float* __restrict__ hoa,
                  const __bf16* __restrict__ bpk,
                  float* __restrict__ out)
{
    __shared__ __align__(16) __bf16 xs[4][2][WSEG];   // 53,248 B, wave-private

    const int qb   = blockIdx.x;          // 0..117
    const int b    = blockIdx.y;          // 0..7
    const int tid  = threadIdx.x;
    const int lane = tid & 63;
    const int wv   = tid >> 6;            // wave 0..3
    const int mlan = lane & 15;
    const int quad = lane >> 4;

    const int q0  = qb * ROWS;
    const int t0  = 16 * q0 - 2048;       // block window origin (sample idx)
    const int twv = t0 + wv * 1024;       // THIS wave's window origin

    const int rbase = 16 * mlan + 8 * quad;   // lane's read offset in wave window

    const float* xb = hoa + (long)b * N_CH * N_SMP;

    f32x4 acc[4][2] = {};                 // [msub][ear]

    // ---- prologue: this wave stages channel 0 into xs[wv][0] ----
    {
        __bf16* xd = &xs[wv][0][0];
        #pragma unroll
        for (int k = 0; k < 13; ++k) {
            const int i4 = lane + 64 * k;
            st4(xd, i4, ldx(xb, twv + 4 * i4));
        }
    }

    for (int c = 0; c < N_CH; ++c) {
        const __bf16* bp = bpk + (long)c * (NKT * 1024) + lane * 8;

        // ---- prime B queue (depth BQD): L2 latency overlaps W preload ----
        bf16x8 BQ0[BQD], BQ1[BQD];
        #pragma unroll
        for (int d = 0; d < BQD; ++d) {
            BQ0[d] = *(const bf16x8*)(bp + d * 1024);
            BQ1[d] = *(const bf16x8*)(bp + d * 1024 + 512);
        }

        const __bf16* xw = &xs[wv][c & 1][0];
        __bf16*       xd = &xs[wv][(c + 1) & 1][0];
        const float*  xn = xb + (long)(c + 1) * N_SMP;   // next channel src

        // ---- preload A window (wave-own LDS): bank s holds f(8s..8s+7) ----
        bf16x8 W[4][8];
        #pragma unroll
        for (int s = 0; s < 4; ++s)
            #pragma unroll
            for (int i = 0; i < 8; ++i)
                W[s][i] = *(const bf16x8*)(xw + rbase + 32 * (8 * s + i));

        float4 sva[7], svb[6];   // staging batches; <=28 regs live at a time

        // ---- 8 groups of 8 K-tiles; per-kt: {BQ refill, MFMA x8, W refill} ----
        #pragma unroll
        for (int g = 0; g < 8; ++g) {
            const int g4 = g & 3;
            #pragma unroll
            for (int i = 0; i < 8; ++i) {
                const int kt = 8 * g + i;
                const int d  = kt % BQD;
                bf16x8 b0 = BQ0[d];
                bf16x8 b1 = BQ1[d];
                const int ktp = (kt + BQD <= 64) ? kt + BQD : 64;   // compile-time
                BQ0[d] = *(const bf16x8*)(bp + ktp * 1024);
                BQ1[d] = *(const bf16x8*)(bp + ktp * 1024 + 512);
                __builtin_amdgcn_s_setprio(1);
                #pragma unroll
                for (int s = 0; s < 4; ++s) {
                    acc[s][0] = __builtin_amdgcn_mfma_f32_16x16x32_bf16(
                                    W[(g4 + s) & 3][i], b0, acc[s][0], 0, 0, 0);
                    acc[s][1] = __builtin_amdgcn_mfma_f32_16x16x32_bf16(
                                    W[(g4 + s) & 3][i], b1, acc[s][1], 0, 0, 0);
                }
                __builtin_amdgcn_s_setprio(0);
                // refill slot i of retiring bank g4 with f(8g+32+i)
                // (dead g=7 refills land in pad: max offset 3311 < WSEG)
                W[g4][i] = *(const bf16x8*)(xw + rbase + 32 * (8 * g + 32 + i));
            }
            // ---- wave-private staging pipeline for channel c+1 ----
            if (c + 1 < N_CH) {
                if (g == 1) {           // issue batch 1 (7 float4)
                    #pragma unroll
                    for (int k = 0; k < 7; ++k)
                        sva[k] = ldx(xn, twv + 4 * (lane + 64 * k));
                } else if (g == 3) {    // write batch 1 (buffer is wave-own)
                    #pragma unroll
                    for (int k = 0; k < 7; ++k)
                        st4(xd, lane + 64 * k, sva[k]);
                } else if (g == 4) {    // issue batch 2 (6 float4)
                    #pragma unroll
                    for (int k = 0; k < 6; ++k)
                        svb[k] = ldx(xn, twv + 4 * (lane + 64 * (7 + k)));
                } else if (g == 6) {    // write batch 2
                    #pragma unroll
                    for (int k = 0; k < 6; ++k)
                        st4(xd, lane + 64 * (7 + k), svb[k]);
                }
            }
        }

        // ---- tail kt = 64: bank s slot 0 holds f(64+8s); BQ slot 64%BQD ----
        {
            bf16x8 b0 = BQ0[64 % BQD];
            bf16x8 b1 = BQ1[64 % BQD];
            __builtin_amdgcn_s_setprio(1);
            #pragma unroll
            for (int s = 0; s < 4; ++s) {
                acc[s][0] = __builtin_amdgcn_mfma_f32_16x16x32_bf16(
                                W[s][0], b0, acc[s][0], 0, 0, 0);
                acc[s][1] = __builtin_amdgcn_mfma_f32_16x16x32_bf16(
                                W[s][0], b1, acc[s][1], 0, 0, 0);
            }
            __builtin_amdgcn_s_setprio(0);
        }
        // no barrier: next channel's reads are from this wave's own segment;
        // ds-write->ds-read ordering is handled by per-wave lgkmcnt.
    }

    // ---- epilogue: C/D layout row = quad*4 + r, col = lane&15 (verified) ----
    const long ob = (long)b * N_EARS * N_SMP;
    #pragma unroll
    for (int s = 0; s < 4; ++s) {
        #pragma unroll
        for (int e = 0; e < N_EARS; ++e) {
            #pragma unroll
            for (int r = 0; r < 4; ++r) {
                const int rl = wv * 64 + s * 16 + quad * 4 + r;
                const int q  = q0 + rl;
                if (q < N_QROWS)
                    out[ob + (long)e * N_SMP + 16 * q + mlan] = acc[s][e][r];
            }
        }
    }
}

// ---------------------------------------------------------------------------
extern "C" void kernel_launch(void* const* d_in, const int* in_sizes, int n_in,
                              void* d_out, int out_size, void* d_ws, size_t ws_size,
                              hipStream_t stream)
{
    const float* hoa = (const float*)d_in[0];   // [8,16,480000] fp32
    const float* h   = (const float*)d_in[1];   // [2,16,2048]  fp32
    float* out       = (float*)d_out;           // [8,2,480000] fp32
    __bf16* bpk      = (__bf16*)d_ws;           // 2,129,920 B filter pack

    const int total_bpk = N_CH * NKT * 2 * 64 * 8;          // 1,064,960
    build_bpk<<<(total_bpk + 255) / 256, 256, 0, stream>>>(h, bpk);

    dim3 grid(QB_PER_B, N_BATCH);
    hoa_bin_gemm<<<grid, BLK, 0, stream>>>(hoa, bpk, out);
}

// Round 8
// 647.144 us; speedup vs baseline: 3.2849x; 1.1990x over previous
//
#include <hip/hip_runtime.h>
#include <hip/hip_bf16.h>

#define N_BATCH 8
#define N_CH    16
#define N_SMP   480000
#define N_EARS  2
#define N_TAP   2048

#define NKT     65                    // K-tiles (of 32) per channel
#define ROWS    256                   // q-rows per block (4 waves x 4 msubs x 16)
#define N_QROWS (N_SMP / 16)          // 30000
#define QB_PER_B ((N_QROWS + ROWS - 1) / ROWS)   // 118
#define XS_LEN  6400                  // bf16 elems per buffer (6160 real + pad for dead refills)
#define NF4     (XS_LEN / 4)          // 1600 float4 staging slots
#define BLK     256
#define BQD     3                     // B prefetch depth (round-4: 6 spills)

typedef __bf16 bf16x8 __attribute__((ext_vector_type(8)));
typedef float  f32x4  __attribute__((ext_vector_type(4)));

// ---------------------------------------------------------------------------
// Prep: pack filters into MFMA-B-fragment order (verified rounds 1-2).
// B[u][n] = h[e][c][2048 - u + n], u = kt*32 + (lane>>4)*8 + j, n = lane&15.
// Flat: (((c*NKT + kt)*2 + e)*64 + lane)*8 + j  -> 16B/lane, coalesced.
// ---------------------------------------------------------------------------
__global__ void build_bpk(const float* __restrict__ h, __bf16* __restrict__ bpk)
{
    const int idx = blockIdx.x * 256 + threadIdx.x;
    const int total = N_CH * NKT * 2 * 64 * 8;
    if (idx >= total) return;

    const int j    = idx & 7;
    const int lane = (idx >> 3) & 63;
    const int e    = (idx >> 9) & 1;
    const int ckt  = idx >> 10;          // c*NKT + kt
    const int kt   = ckt % NKT;
    const int c    = ckt / NKT;

    const int n  = lane & 15;
    const int kq = (lane >> 4) * 8 + j;
    const int u  = kt * 32 + kq;
    const int k  = 2048 - u + n;

    float val = (k >= 0 && k < N_TAP) ? h[((long)e * N_CH + c) * N_TAP + k] : 0.0f;
    bpk[idx] = (__bf16)val;
}

// ---------------------------------------------------------------------------
// Barrier with LGKM-only drain. __syncthreads() makes the compiler emit
// s_waitcnt vmcnt(0) lgkmcnt(0) before s_barrier; the vmcnt(0) is
// semantically unneeded here -- the only cross-wave data at the barrier is
// the LDS staging writes (lgkm). The 6 BQ-prime global loads issued just
// before the barrier are register-destined (wave-local) and may legally stay
// in flight across it (m201's verified raw-barrier pattern / T4).
// ---------------------------------------------------------------------------
__device__ __forceinline__ void barrier_lgkm_only()
{
    asm volatile("s_waitcnt lgkmcnt(0)" ::: "memory");
    __builtin_amdgcn_sched_barrier(0);
    __builtin_amdgcn_s_barrier();
}

// ---------------------------------------------------------------------------
// Main GEMM -- round-3 winner (W[4][8] banked window, spread 1-per-kt
// refills, setprio around MFMA clusters, BQD=3, 434 us / 56.5% MfmaUtil)
// plus two zero-register-delta schedule edits:
//   * barrier_lgkm_only() instead of __syncthreads(): BQ-prime loads stay
//     in flight across the barrier instead of being drained at full L2
//     latency by all 8 CU waves in lockstep, every channel
//   * W preload i-major: kt=0's four fragments issue first, so fine-grained
//     lgkmcnt lets the first MFMA start after ~4 ds_reads instead of 32
// Rounds 4/6/7 lessons: BQD=6 spills (+48 regs); no-LDS thrashes L1 (15x
// Toeplitz redundancy); wave-private staging spills + 2x HBM fetch. The
// cooperative-staged, 128-VGPR round-3 shape is the only spill-free point;
// only zero-pressure schedule edits are admissible on it.
// ---------------------------------------------------------------------------
__global__ __launch_bounds__(BLK, 2)
void hoa_bin_gemm(const float* __restrict__ hoa,
                  const __bf16* __restrict__ bpk,
                  float* __restrict__ out)
{
    __shared__ __align__(16) __bf16 xs[2][XS_LEN];

    const int qb   = blockIdx.x;          // 0..117
    const int b    = blockIdx.y;          // 0..7
    const int tid  = threadIdx.x;
    const int lane = tid & 63;
    const int wv   = tid >> 6;            // wave 0..3
    const int mlan = lane & 15;
    const int quad = lane >> 4;

    const int q0 = qb * ROWS;
    const int t0 = 16 * q0 - 2048;        // sample index of xs[.][0]

    const int abase = wv * 1024 + 16 * mlan + 8 * quad;

    const float* xb = hoa + (long)b * N_CH * N_SMP;

    f32x4 acc[4][2] = {};                 // [msub][ear]

    // ---- prologue: stage channel 0 into xs[0] ----
    {
        float4 v[7];
        #pragma unroll
        for (int k = 0; k < 7; ++k) {
            const int i4 = tid + k * BLK;
            const int t  = t0 + 4 * i4;
            float4 w = {0.f, 0.f, 0.f, 0.f};
            if (i4 < NF4 && t >= 0 && t <= N_SMP - 4) w = *(const float4*)(xb + t);
            v[k] = w;
        }
        #pragma unroll
        for (int k = 0; k < 7; ++k) {
            const int i4 = tid + k * BLK;
            if (i4 < NF4) {
                union { __bf16 hh[4]; uint2 u; } pk;
                pk.hh[0] = (__bf16)v[k].x; pk.hh[1] = (__bf16)v[k].y;
                pk.hh[2] = (__bf16)v[k].z; pk.hh[3] = (__bf16)v[k].w;
                *(uint2*)(&xs[0][4 * i4]) = pk.u;
            }
        }
    }

    for (int c = 0; c < N_CH; ++c) {
        const __bf16* bp = bpk + (long)c * (NKT * 1024) + lane * 8;

        // ---- prime B queue (depth BQD) before barrier: loads stay in
        //      flight ACROSS the lgkm-only barrier (not drained) ----
        bf16x8 BQ0[BQD], BQ1[BQD];
        #pragma unroll
        for (int d = 0; d < BQD; ++d) {
            BQ0[d] = *(const bf16x8*)(bp + d * 1024);
            BQ1[d] = *(const bf16x8*)(bp + d * 1024 + 512);
        }

        barrier_lgkm_only();   // xs[c&1] staged; previous readers done

        const __bf16* xw = &xs[c & 1][0];

        // ---- preload A window, i-major: kt=0's four reads issue first.
        //      bank s holds f(8s..8s+7) ----
        bf16x8 W[4][8];
        #pragma unroll
        for (int i = 0; i < 8; ++i)
            #pragma unroll
            for (int s = 0; s < 4; ++s)
                W[s][i] = *(const bf16x8*)(xw + abase + 32 * (8 * s + i));

        float4 sreg[7];    // staging regs — live groups 2..7 only

        // ---- 8 groups of 8 K-tiles; per-kt: {BQ refill, MFMA x8, W refill} ----
        #pragma unroll
        for (int g = 0; g < 8; ++g) {
            const int g4 = g & 3;
            #pragma unroll
            for (int i = 0; i < 8; ++i) {
                const int kt = 8 * g + i;
                const int d  = kt % BQD;
                bf16x8 b0 = BQ0[d];
                bf16x8 b1 = BQ1[d];
                const int ktp = (kt + BQD <= 64) ? kt + BQD : 64;   // compile-time
                BQ0[d] = *(const bf16x8*)(bp + ktp * 1024);
                BQ1[d] = *(const bf16x8*)(bp + ktp * 1024 + 512);
                __builtin_amdgcn_s_setprio(1);
                #pragma unroll
                for (int s = 0; s < 4; ++s) {
                    acc[s][0] = __builtin_amdgcn_mfma_f32_16x16x32_bf16(
                                    W[(g4 + s) & 3][i], b0, acc[s][0], 0, 0, 0);
                    acc[s][1] = __builtin_amdgcn_mfma_f32_16x16x32_bf16(
                                    W[(g4 + s) & 3][i], b1, acc[s][1], 0, 0, 0);
                }
                __builtin_amdgcn_s_setprio(0);
                // refill slot i of retiring bank g4 with f(8g+32+i)
                // (dead after msub 0 used it this kt; g=7 refill lands in pad)
                W[g4][i] = *(const bf16x8*)(xw + abase + 32 * (8 * g + 32 + i));
            }
            // issue next-channel staging loads after group 1 (off the
            // BQ-prime vmcnt window; sreg live range = groups 2..7 only)
            if (g == 1 && c + 1 < N_CH) {
                const float* xc = xb + (long)(c + 1) * N_SMP;
                #pragma unroll
                for (int k = 0; k < 7; ++k) {
                    const int i4 = tid + k * BLK;
                    const int t  = t0 + 4 * i4;
                    float4 w = {0.f, 0.f, 0.f, 0.f};
                    if (i4 < NF4 && t >= 0 && t <= N_SMP - 4) w = *(const float4*)(xc + t);
                    sreg[k] = w;
                }
            }
        }

        // ---- tail kt = 64: bank s slot 0 holds f(64+8s); BQ slot 64%BQD ----
        {
            bf16x8 b0 = BQ0[64 % BQD];
            bf16x8 b1 = BQ1[64 % BQD];
            __builtin_amdgcn_s_setprio(1);
            #pragma unroll
            for (int s = 0; s < 4; ++s) {
                acc[s][0] = __builtin_amdgcn_mfma_f32_16x16x32_bf16(
                                W[s][0], b0, acc[s][0], 0, 0, 0);
                acc[s][1] = __builtin_amdgcn_mfma_f32_16x16x32_bf16(
                                W[s][0], b1, acc[s][1], 0, 0, 0);
            }
            __builtin_amdgcn_s_setprio(0);
        }

        // ---- write staged channel c+1 into the other buffer ----
        if (c + 1 < N_CH) {
            __bf16* xd = &xs[(c + 1) & 1][0];
            #pragma unroll
            for (int k = 0; k < 7; ++k) {
                const int i4 = tid + k * BLK;
                if (i4 < NF4) {
                    union { __bf16 hh[4]; uint2 u; } pk;
                    pk.hh[0] = (__bf16)sreg[k].x; pk.hh[1] = (__bf16)sreg[k].y;
                    pk.hh[2] = (__bf16)sreg[k].z; pk.hh[3] = (__bf16)sreg[k].w;
                    *(uint2*)(&xd[4 * i4]) = pk.u;
                }
            }
        }
    }

    // ---- epilogue: C/D layout row = quad*4 + r, col = lane&15 (verified) ----
    const long ob = (long)b * N_EARS * N_SMP;
    #pragma unroll
    for (int s = 0; s < 4; ++s) {
        #pragma unroll
        for (int e = 0; e < N_EARS; ++e) {
            #pragma unroll
            for (int r = 0; r < 4; ++r) {
                const int rl = wv * 64 + s * 16 + quad * 4 + r;
                const int q  = q0 + rl;
                if (q < N_QROWS)
                    out[ob + (long)e * N_SMP + 16 * q + mlan] = acc[s][e][r];
            }
        }
    }
}

// ---------------------------------------------------------------------------
extern "C" void kernel_launch(void* const* d_in, const int* in_sizes, int n_in,
                              void* d_out, int out_size, void* d_ws, size_t ws_size,
                              hipStream_t stream)
{
    const float* hoa = (const float*)d_in[0];   // [8,16,480000] fp32
    const float* h   = (const float*)d_in[1];   // [2,16,2048]  fp32
    float* out       = (float*)d_out;           // [8,2,480000] fp32
    __bf16* bpk      = (__bf16*)d_ws;           // 2,129,920 B filter pack

    const int total_bpk = N_CH * NKT * 2 * 64 * 8;          // 1,064,960
    build_bpk<<<(total_bpk + 255) / 256, 256, 0, stream>>>(h, bpk);

    dim3 grid(QB_PER_B, N_BATCH);
    hoa_bin_gemm<<<grid, BLK, 0, stream>>>(hoa, bpk, out);
}